// Round 1
// baseline (388.808 us; speedup 1.0000x reference)
//
#include <hip/hip_runtime.h>

#define BB   16
#define CINC 64
#define COUTC 64
#define HH   128
#define WW   128

__device__ __forceinline__ float lrelu(float v) {
    return fmaxf(v, 0.f) + 0.01f * fminf(v, 0.f);
}

// ---------------- Kernel A: hypernet stages 1-3 -> k2 [B][32][9] ----------------
__global__ void hyper_k2_kernel(const float* __restrict__ h,
                                const float* __restrict__ fc_w,
                                const float* __restrict__ fc_b,
                                const float* __restrict__ w1,
                                const float* __restrict__ b1,
                                const float* __restrict__ w2,
                                const float* __restrict__ b2,
                                float* __restrict__ k2_out) {
    int b = blockIdx.x;
    int t = threadIdx.x;
    __shared__ float hs[8];
    __shared__ float k0s[144];   // [16][9]
    __shared__ float k1s[288];   // [32][9]
    if (t < 8) hs[t] = h[b * 8 + t];
    __syncthreads();
    if (t < 144) {
        float acc = fc_b[t];
        #pragma unroll
        for (int c = 0; c < 8; ++c) acc += hs[c] * fc_w[t * 8 + c];
        k0s[t] = lrelu(acc);
    }
    __syncthreads();
    for (int idx = t; idx < 288; idx += 256) {
        int o = idx / 9, tap = idx % 9;
        float acc = b1[o];
        #pragma unroll
        for (int c = 0; c < 16; ++c) acc += w1[o * 16 + c] * k0s[c * 9 + tap];
        k1s[idx] = lrelu(acc);
    }
    __syncthreads();
    for (int idx = t; idx < 288; idx += 256) {
        int o = idx / 9, tap = idx % 9;
        float acc = b2[o];
        #pragma unroll
        for (int c = 0; c < 32; ++c) acc += w2[o * 32 + c] * k1s[c * 9 + tap];
        k2_out[b * 288 + idx] = lrelu(acc);
    }
}

// ------- Kernel B: wF[b][ci][tap][co] = sum_c w3[(co*64+ci)*32+c]*k2[b][c][tap] + b3 -------
__global__ void hyper_w_kernel(const float* __restrict__ k2,
                               const float* __restrict__ w3,
                               const float* __restrict__ b3,
                               float* __restrict__ wF) {
    int co = blockIdx.x;   // 0..63
    int b  = blockIdx.y;   // 0..15
    int ci = threadIdx.x;  // 0..63
    __shared__ float k2s[288];
    for (int i = ci; i < 288; i += 64) k2s[i] = k2[b * 288 + i];
    __syncthreads();
    int o = co * CINC + ci;
    float wrow[32];
    #pragma unroll
    for (int c = 0; c < 32; ++c) wrow[c] = w3[o * 32 + c];
    float bb = b3[o];
    #pragma unroll
    for (int tap = 0; tap < 9; ++tap) {
        float acc = bb;
        #pragma unroll
        for (int c = 0; c < 32; ++c) acc += wrow[c] * k2s[c * 9 + tap];
        wF[((b * CINC + ci) * 9 + tap) * COUTC + co] = acc;
    }
}

// ---------------- Kernel C: main per-sample conv ----------------
// block = (b, 16x16 spatial tile, all 64 cout). 256 threads.
// thread (cog 0..7, pxg 0..31): 8 co x 8 px accumulators.
#define TS 16
#define CK 16
#define XRS 20   // padded row stride (floats), keeps 16B alignment, 20%32 banks spread

__global__ __launch_bounds__(256, 2)
void conv_main_kernel(const float* __restrict__ x,
                      const float* __restrict__ wF,
                      const float* __restrict__ bias,
                      float* __restrict__ out) {
    __shared__ __align__(16) float xs[CK][18][XRS];     // 23040 B
    __shared__ __align__(16) float wsh[CK * 9 * COUTC]; // 36864 B

    const int b   = blockIdx.z;
    const int tx0 = blockIdx.x * TS;
    const int ty0 = blockIdx.y * TS;
    const int tid = threadIdx.x;
    const int cog = tid >> 5;          // 0..7  -> co = cog*8 + o
    const int pxg = tid & 31;          // 0..31
    const int r   = pxg >> 1;          // row in tile 0..15
    const int c0  = (pxg & 1) * 8;     // col base 0 or 8

    float acc[8][8];
    #pragma unroll
    for (int o = 0; o < 8; ++o)
        #pragma unroll
        for (int j = 0; j < 8; ++j) acc[o][j] = 0.f;

    float bv[8];
    #pragma unroll
    for (int o = 0; o < 8; ++o) bv[o] = bias[cog * 8 + o];

    const float* xb = x + (size_t)b * CINC * HH * WW;

    for (int ci0 = 0; ci0 < CINC; ci0 += CK) {
        // ---- stage x chunk (with halo, zero-padded) ----
        for (int idx = tid; idx < CK * 18 * 18; idx += 256) {
            int ci  = idx / (18 * 18);
            int rem = idx - ci * (18 * 18);
            int yy  = rem / 18;
            int xx  = rem - yy * 18;
            int gy = ty0 - 1 + yy;
            int gx = tx0 - 1 + xx;
            float v = 0.f;
            if (gy >= 0 && gy < HH && gx >= 0 && gx < WW)
                v = xb[(ci0 + ci) * (HH * WW) + gy * WW + gx];
            xs[ci][yy][xx] = v;
        }
        // ---- stage weight chunk: flat contiguous copy [ci][tap][co] ----
        {
            const float4* wsrc = (const float4*)(wF + (size_t)(b * CINC + ci0) * (9 * COUTC));
            float4* wdst = (float4*)wsh;
            for (int idx = tid; idx < CK * 9 * COUTC / 4; idx += 256)
                wdst[idx] = wsrc[idx];
        }
        __syncthreads();

        #pragma unroll 1
        for (int ci = 0; ci < CK; ++ci) {
            // x row fragments: 10 values per ky
            float xr[3][10];
            #pragma unroll
            for (int ky = 0; ky < 3; ++ky) {
                const float* base = &xs[ci][r + ky][c0];
                float4 a = *(const float4*)(base);
                float4 q = *(const float4*)(base + 4);
                float2 e = *(const float2*)(base + 8);
                xr[ky][0] = a.x; xr[ky][1] = a.y; xr[ky][2] = a.z; xr[ky][3] = a.w;
                xr[ky][4] = q.x; xr[ky][5] = q.y; xr[ky][6] = q.z; xr[ky][7] = q.w;
                xr[ky][8] = e.x; xr[ky][9] = e.y;
            }
            #pragma unroll
            for (int ky = 0; ky < 3; ++ky) {
                #pragma unroll
                for (int kx = 0; kx < 3; ++kx) {
                    const float* wp = &wsh[(ci * 9 + ky * 3 + kx) * COUTC + cog * 8];
                    float4 w0 = *(const float4*)(wp);
                    float4 w1v = *(const float4*)(wp + 4);
                    float wv[8] = {w0.x, w0.y, w0.z, w0.w, w1v.x, w1v.y, w1v.z, w1v.w};
                    #pragma unroll
                    for (int o = 0; o < 8; ++o)
                        #pragma unroll
                        for (int j = 0; j < 8; ++j)
                            acc[o][j] += wv[o] * xr[ky][j + kx];
                }
            }
        }
        __syncthreads();
    }

    // ---- epilogue: bias + store, 2x float4 per co ----
    #pragma unroll
    for (int o = 0; o < 8; ++o) {
        int co = cog * 8 + o;
        float* op = out + (((size_t)(b * COUTC + co) * HH + (ty0 + r)) * WW + tx0 + c0);
        float4 s0, s1;
        s0.x = acc[o][0] + bv[o]; s0.y = acc[o][1] + bv[o];
        s0.z = acc[o][2] + bv[o]; s0.w = acc[o][3] + bv[o];
        s1.x = acc[o][4] + bv[o]; s1.y = acc[o][5] + bv[o];
        s1.z = acc[o][6] + bv[o]; s1.w = acc[o][7] + bv[o];
        *(float4*)(op)     = s0;
        *(float4*)(op + 4) = s1;
    }
}

extern "C" void kernel_launch(void* const* d_in, const int* in_sizes, int n_in,
                              void* d_out, int out_size, void* d_ws, size_t ws_size,
                              hipStream_t stream) {
    const float* x    = (const float*)d_in[0];
    const float* h    = (const float*)d_in[1];
    const float* fc_w = (const float*)d_in[2];
    const float* fc_b = (const float*)d_in[3];
    const float* w1   = (const float*)d_in[4];
    const float* b1   = (const float*)d_in[5];
    const float* w2   = (const float*)d_in[6];
    const float* b2   = (const float*)d_in[7];
    const float* w3   = (const float*)d_in[8];
    const float* b3   = (const float*)d_in[9];
    const float* bias = (const float*)d_in[10];
    float* out = (float*)d_out;

    // workspace layout: k2 [16*288] floats, then wF [16*64*9*64] floats
    float* k2 = (float*)d_ws;
    float* wF = k2 + BB * 288;   // offset 4608 floats (16B aligned)

    hyper_k2_kernel<<<dim3(BB), dim3(256), 0, stream>>>(h, fc_w, fc_b, w1, b1, w2, b2, k2);
    hyper_w_kernel<<<dim3(COUTC, BB), dim3(64), 0, stream>>>(k2, w3, b3, wF);
    conv_main_kernel<<<dim3(WW / TS, HH / TS, BB), dim3(256), 0, stream>>>(x, wF, bias, out);
}

// Round 2
// 234.824 us; speedup vs baseline: 1.6557x; 1.6557x over previous
//
#include <hip/hip_runtime.h>

#define BB   16
#define CINC 64
#define COUTC 64
#define HH   128
#define WW   128

typedef _Float16 f16x8 __attribute__((ext_vector_type(8)));
typedef float f32x4 __attribute__((ext_vector_type(4)));

__device__ __forceinline__ float lrelu(float v) {
    return fmaxf(v, 0.f) + 0.01f * fminf(v, 0.f);
}

// ---------------- Kernel A: hypernet stages 1-3 -> k2 [B][32][9] ----------------
__global__ void hyper_k2_kernel(const float* __restrict__ h,
                                const float* __restrict__ fc_w,
                                const float* __restrict__ fc_b,
                                const float* __restrict__ w1,
                                const float* __restrict__ b1,
                                const float* __restrict__ w2,
                                const float* __restrict__ b2,
                                float* __restrict__ k2_out) {
    int b = blockIdx.x;
    int t = threadIdx.x;
    __shared__ float hs[8];
    __shared__ float k0s[144];   // [16][9]
    __shared__ float k1s[288];   // [32][9]
    if (t < 8) hs[t] = h[b * 8 + t];
    __syncthreads();
    if (t < 144) {
        float acc = fc_b[t];
        #pragma unroll
        for (int c = 0; c < 8; ++c) acc += hs[c] * fc_w[t * 8 + c];
        k0s[t] = lrelu(acc);
    }
    __syncthreads();
    for (int idx = t; idx < 288; idx += 256) {
        int o = idx / 9, tap = idx % 9;
        float acc = b1[o];
        #pragma unroll
        for (int c = 0; c < 16; ++c) acc += w1[o * 16 + c] * k0s[c * 9 + tap];
        k1s[idx] = lrelu(acc);
    }
    __syncthreads();
    for (int idx = t; idx < 288; idx += 256) {
        int o = idx / 9, tap = idx % 9;
        float acc = b2[o];
        #pragma unroll
        for (int c = 0; c < 32; ++c) acc += w2[o * 32 + c] * k1s[c * 9 + tap];
        k2_out[b * 288 + idx] = lrelu(acc);
    }
}

// ------- Kernel B: fragment-ordered fp16 weights for MFMA B-operand -------
// W[b][ci][tap][co] value goes to frag = ((b*9+tap)*2 + chunk)*4 + coT,
// element [lane = (g<<4)|(co&15)][j], where chunk=ci>>5, g=(ci>>3)&3, j=ci&7.
// Each frag is 1KB = exactly one wave's B-frag for mfma_f32_16x16x32_f16.
__global__ void hyper_wfrag_kernel(const float* __restrict__ k2,
                                   const float* __restrict__ w3,
                                   const float* __restrict__ b3,
                                   _Float16* __restrict__ wf) {
    int co = blockIdx.x;   // 0..63
    int b  = blockIdx.y;   // 0..15
    int ci = threadIdx.x;  // 0..63
    __shared__ float k2s[288];
    for (int i = ci; i < 288; i += 64) k2s[i] = k2[b * 288 + i];
    __syncthreads();
    int o = co * CINC + ci;
    float wrow[32];
    #pragma unroll
    for (int c = 0; c < 32; ++c) wrow[c] = w3[o * 32 + c];
    float bb = b3[o];
    int chunk = ci >> 5;
    int g     = (ci >> 3) & 3;
    int j     = ci & 7;
    int lane  = (g << 4) | (co & 15);
    int coT   = co >> 4;
    #pragma unroll
    for (int tap = 0; tap < 9; ++tap) {
        float acc = bb;
        #pragma unroll
        for (int c = 0; c < 32; ++c) acc += wrow[c] * k2s[c * 9 + tap];
        size_t frag = ((size_t)(b * 9 + tap) * 2 + chunk) * 4 + coT;
        wf[frag * 512 + lane * 8 + j] = (_Float16)acc;
    }
}

// ---------------- Kernel C: MFMA conv ----------------
// Block: 128 threads (2 waves), tile 16 rows x 16 cols x all 64 co.
// Wave w owns 8 image rows; per row (M-tile, 16 px) x 4 co-tiles of 16.
// X LDS: [324 px][plane hi/lo][32 ci] fp16, 128B per pixel, slot-rotated by p.
__global__ __launch_bounds__(128)
void conv_mfma_kernel(const float* __restrict__ x,
                      const _Float16* __restrict__ wf,
                      const float* __restrict__ bias,
                      float* __restrict__ out) {
    __shared__ __align__(16) char xs[324 * 128];   // 41472 B

    const int b   = blockIdx.z;
    const int x0  = blockIdx.x * 16;
    const int y0  = blockIdx.y * 16;
    const int tid = threadIdx.x;
    const int lane = tid & 63;
    const int w    = tid >> 6;       // wave 0..1
    const int lc   = lane & 15;
    const int g    = lane >> 4;      // k-group / x-quad

    f32x4 acc[8][4];
    #pragma unroll
    for (int m = 0; m < 8; ++m)
        #pragma unroll
        for (int n = 0; n < 4; ++n)
            acc[m][n] = (f32x4){0.f, 0.f, 0.f, 0.f};

    const float* xb = x + (size_t)b * CINC * HH * WW;
    const f16x8* wfb = (const f16x8*)wf;

    for (int chunk = 0; chunk < 2; ++chunk) {
        if (chunk) __syncthreads();
        // ---- stage x chunk: fp32 -> (hi,lo) fp16, swizzled LDS ----
        for (int idx = tid; idx < 16 * 324; idx += 128) {
            int cp   = idx / 324;            // ci-pair 0..15
            int p    = idx - cp * 324;       // pixel 0..323
            int srow = p / 18;
            int scol = p - srow * 18;
            int gy = y0 - 1 + srow;
            int gx = x0 - 1 + scol;
            int ci = chunk * 32 + cp * 2;
            float v0 = 0.f, v1 = 0.f;
            if (gy >= 0 && gy < HH && gx >= 0 && gx < WW) {
                const float* px = xb + (size_t)ci * (HH * WW) + gy * WW + gx;
                v0 = px[0];
                v1 = px[HH * WW];
            }
            _Float16 h0 = (_Float16)v0, h1 = (_Float16)v1;
            _Float16 l0 = (_Float16)(v0 - (float)h0);
            _Float16 l1 = (_Float16)(v1 - (float)h1);
            unsigned hp = (unsigned)__builtin_bit_cast(unsigned short, h0) |
                          ((unsigned)__builtin_bit_cast(unsigned short, h1) << 16);
            unsigned lp = (unsigned)__builtin_bit_cast(unsigned short, l0) |
                          ((unsigned)__builtin_bit_cast(unsigned short, l1) << 16);
            char* base = xs + p * 128 + (cp & 3) * 4;
            int gsl = cp >> 2;
            *(unsigned*)(base + (((gsl)     + p) & 7) * 16) = hp;   // hi plane
            *(unsigned*)(base + (((4 + gsl) + p) & 7) * 16) = lp;   // lo plane
        }
        __syncthreads();

        // ---- B-frag prefetch for tap 0 ----
        f16x8 B0[4], B1[4];
        {
            size_t fb = ((size_t)(b * 9 + 0) * 2 + chunk) * 4;
            #pragma unroll
            for (int n = 0; n < 4; ++n) B0[n] = wfb[(fb + n) * 64 + lane];
        }

        #pragma unroll 1
        for (int tap = 0; tap < 9; ++tap) {
            if (tap < 8) {
                size_t fb = ((size_t)(b * 9 + tap + 1) * 2 + chunk) * 4;
                #pragma unroll
                for (int n = 0; n < 4; ++n) B1[n] = wfb[(fb + n) * 64 + lane];
            }
            int ky = tap / 3;
            int kx = tap - ky * 3;
            int scol = lc + kx;
            #pragma unroll
            for (int m = 0; m < 8; ++m) {
                int srow = w * 8 + m + ky;
                int p = srow * 18 + scol;
                const char* pb = xs + p * 128;
                f16x8 Ah = *(const f16x8*)(pb + (((g)     + p) & 7) * 16);
                f16x8 Al = *(const f16x8*)(pb + (((4 + g) + p) & 7) * 16);
                #pragma unroll
                for (int n = 0; n < 4; ++n) {
                    acc[m][n] = __builtin_amdgcn_mfma_f32_16x16x32_f16(Ah, B0[n], acc[m][n], 0, 0, 0);
                    acc[m][n] = __builtin_amdgcn_mfma_f32_16x16x32_f16(Al, B0[n], acc[m][n], 0, 0, 0);
                }
            }
            if (tap < 8) {
                #pragma unroll
                for (int n = 0; n < 4; ++n) B0[n] = B1[n];
            }
        }
    }

    // ---- epilogue: bias + coalesced dwordx4 stores ----
    float bval[4];
    #pragma unroll
    for (int n = 0; n < 4; ++n) bval[n] = bias[n * 16 + lc];
    #pragma unroll
    for (int m = 0; m < 8; ++m) {
        int y  = y0 + w * 8 + m;
        int xx = x0 + g * 4;
        #pragma unroll
        for (int n = 0; n < 4; ++n) {
            int co = n * 16 + lc;
            f32x4 r = acc[m][n];
            r += bval[n];
            *(f32x4*)(out + (((size_t)(b * COUTC + co) * HH + y) * WW + xx)) = r;
        }
    }
}

extern "C" void kernel_launch(void* const* d_in, const int* in_sizes, int n_in,
                              void* d_out, int out_size, void* d_ws, size_t ws_size,
                              hipStream_t stream) {
    const float* x    = (const float*)d_in[0];
    const float* h    = (const float*)d_in[1];
    const float* fc_w = (const float*)d_in[2];
    const float* fc_b = (const float*)d_in[3];
    const float* w1   = (const float*)d_in[4];
    const float* b1   = (const float*)d_in[5];
    const float* w2   = (const float*)d_in[6];
    const float* b2   = (const float*)d_in[7];
    const float* w3   = (const float*)d_in[8];
    const float* b3   = (const float*)d_in[9];
    const float* bias = (const float*)d_in[10];
    float* out = (float*)d_out;

    // ws layout: k2 [16*288] f32 (18432 B, 1KB-aligned end), then wf fragment
    // array: 16b * 9tap * 2chunk * 4coT frags x 1KB fp16 = 1179648 B.
    float* k2 = (float*)d_ws;
    _Float16* wfrag = (_Float16*)((char*)d_ws + 18432);

    hyper_k2_kernel<<<dim3(BB), dim3(256), 0, stream>>>(h, fc_w, fc_b, w1, b1, w2, b2, k2);
    hyper_wfrag_kernel<<<dim3(COUTC, BB), dim3(64), 0, stream>>>(k2, w3, b3, wfrag);
    conv_mfma_kernel<<<dim3(WW / 16, HH / 16, BB), dim3(128), 0, stream>>>(x, wfrag, bias, out);
}

// Round 3
// 195.056 us; speedup vs baseline: 1.9933x; 1.2039x over previous
//
#include <hip/hip_runtime.h>

#define BB   16
#define CINC 64
#define COUTC 64
#define HH   128
#define WW   128

typedef _Float16 f16x8 __attribute__((ext_vector_type(8)));
typedef _Float16 f16x4 __attribute__((ext_vector_type(4)));
typedef float f32x4 __attribute__((ext_vector_type(4)));

__device__ __forceinline__ float lrelu(float v) {
    return fmaxf(v, 0.f) + 0.01f * fminf(v, 0.f);
}

// ================= Fallback path (round-2 kernels, known-good) =================
__global__ void hyper_k2_kernel(const float* __restrict__ h,
                                const float* __restrict__ fc_w,
                                const float* __restrict__ fc_b,
                                const float* __restrict__ w1,
                                const float* __restrict__ b1,
                                const float* __restrict__ w2,
                                const float* __restrict__ b2,
                                float* __restrict__ k2_out) {
    int b = blockIdx.x;
    int t = threadIdx.x;
    __shared__ float hs[8];
    __shared__ float k0s[144];
    __shared__ float k1s[288];
    if (t < 8) hs[t] = h[b * 8 + t];
    __syncthreads();
    if (t < 144) {
        float acc = fc_b[t];
        #pragma unroll
        for (int c = 0; c < 8; ++c) acc += hs[c] * fc_w[t * 8 + c];
        k0s[t] = lrelu(acc);
    }
    __syncthreads();
    for (int idx = t; idx < 288; idx += 256) {
        int o = idx / 9, tap = idx % 9;
        float acc = b1[o];
        #pragma unroll
        for (int c = 0; c < 16; ++c) acc += w1[o * 16 + c] * k0s[c * 9 + tap];
        k1s[idx] = lrelu(acc);
    }
    __syncthreads();
    for (int idx = t; idx < 288; idx += 256) {
        int o = idx / 9, tap = idx % 9;
        float acc = b2[o];
        #pragma unroll
        for (int c = 0; c < 32; ++c) acc += w2[o * 32 + c] * k1s[c * 9 + tap];
        k2_out[b * 288 + idx] = lrelu(acc);
    }
}

__global__ void hyper_wfrag_kernel(const float* __restrict__ k2,
                                   const float* __restrict__ w3,
                                   const float* __restrict__ b3,
                                   _Float16* __restrict__ wf) {
    int co = blockIdx.x;
    int b  = blockIdx.y;
    int ci = threadIdx.x;
    __shared__ float k2s[288];
    for (int i = ci; i < 288; i += 64) k2s[i] = k2[b * 288 + i];
    __syncthreads();
    int o = co * CINC + ci;
    float wrow[32];
    #pragma unroll
    for (int c = 0; c < 32; ++c) wrow[c] = w3[o * 32 + c];
    float bb = b3[o];
    int chunk = ci >> 5;
    int g     = (ci >> 3) & 3;
    int j     = ci & 7;
    int lane  = (g << 4) | (co & 15);
    int coT   = co >> 4;
    #pragma unroll
    for (int tap = 0; tap < 9; ++tap) {
        float acc = bb;
        #pragma unroll
        for (int c = 0; c < 32; ++c) acc += wrow[c] * k2s[c * 9 + tap];
        size_t frag = ((size_t)(b * 9 + tap) * 2 + chunk) * 4 + coT;
        wf[frag * 512 + lane * 8 + j] = (_Float16)acc;
    }
}

__global__ __launch_bounds__(128)
void conv_mfma_kernel(const float* __restrict__ x,
                      const _Float16* __restrict__ wf,
                      const float* __restrict__ bias,
                      float* __restrict__ out) {
    __shared__ __align__(16) char xs[324 * 128];
    const int b   = blockIdx.z;
    const int x0  = blockIdx.x * 16;
    const int y0  = blockIdx.y * 16;
    const int tid = threadIdx.x;
    const int lane = tid & 63;
    const int w    = tid >> 6;
    const int lc   = lane & 15;
    const int g    = lane >> 4;

    f32x4 acc[8][4];
    #pragma unroll
    for (int m = 0; m < 8; ++m)
        #pragma unroll
        for (int n = 0; n < 4; ++n)
            acc[m][n] = (f32x4){0.f, 0.f, 0.f, 0.f};

    const float* xb = x + (size_t)b * CINC * HH * WW;
    const f16x8* wfb = (const f16x8*)wf;

    for (int chunk = 0; chunk < 2; ++chunk) {
        if (chunk) __syncthreads();
        for (int idx = tid; idx < 16 * 324; idx += 128) {
            int cp   = idx / 324;
            int p    = idx - cp * 324;
            int srow = p / 18;
            int scol = p - srow * 18;
            int gy = y0 - 1 + srow;
            int gx = x0 - 1 + scol;
            int ci = chunk * 32 + cp * 2;
            float v0 = 0.f, v1 = 0.f;
            if (gy >= 0 && gy < HH && gx >= 0 && gx < WW) {
                const float* px = xb + (size_t)ci * (HH * WW) + gy * WW + gx;
                v0 = px[0];
                v1 = px[HH * WW];
            }
            _Float16 h0 = (_Float16)v0, h1 = (_Float16)v1;
            _Float16 l0 = (_Float16)(v0 - (float)h0);
            _Float16 l1 = (_Float16)(v1 - (float)h1);
            unsigned hp = (unsigned)__builtin_bit_cast(unsigned short, h0) |
                          ((unsigned)__builtin_bit_cast(unsigned short, h1) << 16);
            unsigned lp = (unsigned)__builtin_bit_cast(unsigned short, l0) |
                          ((unsigned)__builtin_bit_cast(unsigned short, l1) << 16);
            char* base = xs + p * 128 + (cp & 3) * 4;
            int gsl = cp >> 2;
            *(unsigned*)(base + (((gsl)     + p) & 7) * 16) = hp;
            *(unsigned*)(base + (((4 + gsl) + p) & 7) * 16) = lp;
        }
        __syncthreads();

        f16x8 B0[4], B1[4];
        {
            size_t fb = ((size_t)(b * 9 + 0) * 2 + chunk) * 4;
            #pragma unroll
            for (int n = 0; n < 4; ++n) B0[n] = wfb[(fb + n) * 64 + lane];
        }
        #pragma unroll 1
        for (int tap = 0; tap < 9; ++tap) {
            if (tap < 8) {
                size_t fb = ((size_t)(b * 9 + tap + 1) * 2 + chunk) * 4;
                #pragma unroll
                for (int n = 0; n < 4; ++n) B1[n] = wfb[(fb + n) * 64 + lane];
            }
            int ky = tap / 3;
            int kx = tap - ky * 3;
            int scol = lc + kx;
            #pragma unroll
            for (int m = 0; m < 8; ++m) {
                int srow = w * 8 + m + ky;
                int p = srow * 18 + scol;
                const char* pb = xs + p * 128;
                f16x8 Ah = *(const f16x8*)(pb + (((g)     + p) & 7) * 16);
                f16x8 Al = *(const f16x8*)(pb + (((4 + g) + p) & 7) * 16);
                #pragma unroll
                for (int n = 0; n < 4; ++n) {
                    acc[m][n] = __builtin_amdgcn_mfma_f32_16x16x32_f16(Ah, B0[n], acc[m][n], 0, 0, 0);
                    acc[m][n] = __builtin_amdgcn_mfma_f32_16x16x32_f16(Al, B0[n], acc[m][n], 0, 0, 0);
                }
            }
            if (tap < 8) {
                #pragma unroll
                for (int n = 0; n < 4; ++n) B0[n] = B1[n];
            }
        }
    }

    float bval[4];
    #pragma unroll
    for (int n = 0; n < 4; ++n) bval[n] = bias[n * 16 + lc];
    #pragma unroll
    for (int m = 0; m < 8; ++m) {
        int y  = y0 + w * 8 + m;
        int xx = x0 + g * 4;
        #pragma unroll
        for (int n = 0; n < 4; ++n) {
            int co = n * 16 + lc;
            f32x4 r = acc[m][n];
            r += bval[n];
            *(f32x4*)(out + (((size_t)(b * COUTC + co) * HH + y) * WW + xx)) = r;
        }
    }
}

// ================= Main path =================
// ---- Kernel 1: fused hypernet (recompute k2 per block) + zero-page init ----
__global__ void hyper_fused_kernel(const float* __restrict__ h,
                                   const float* __restrict__ fc_w,
                                   const float* __restrict__ fc_b,
                                   const float* __restrict__ w1,
                                   const float* __restrict__ b1,
                                   const float* __restrict__ w2,
                                   const float* __restrict__ b2,
                                   const float* __restrict__ w3,
                                   const float* __restrict__ b3,
                                   _Float16* __restrict__ wf,
                                   float* __restrict__ zp) {
    int co = blockIdx.x;   // 0..63
    int b  = blockIdx.y;   // 0..15
    int t  = threadIdx.x;  // 0..63
    __shared__ float hs[8];
    __shared__ float k0s[144];
    __shared__ float k1s[288];
    __shared__ float k2s[288];
    if (t < 8) hs[t] = h[b * 8 + t];
    if (co == 0 && b == 0) ((f32x4*)zp)[t] = (f32x4){0.f, 0.f, 0.f, 0.f};  // 1KB zeros
    __syncthreads();
    for (int i = t; i < 144; i += 64) {
        float a = fc_b[i];
        #pragma unroll
        for (int c = 0; c < 8; ++c) a += hs[c] * fc_w[i * 8 + c];
        k0s[i] = lrelu(a);
    }
    __syncthreads();
    for (int i = t; i < 288; i += 64) {
        int o = i / 9, tap = i % 9;
        float a = b1[o];
        #pragma unroll
        for (int c = 0; c < 16; ++c) a += w1[o * 16 + c] * k0s[c * 9 + tap];
        k1s[i] = lrelu(a);
    }
    __syncthreads();
    for (int i = t; i < 288; i += 64) {
        int o = i / 9, tap = i % 9;
        float a = b2[o];
        #pragma unroll
        for (int c = 0; c < 32; ++c) a += w2[o * 32 + c] * k1s[c * 9 + tap];
        k2s[i] = lrelu(a);
    }
    __syncthreads();
    int ci = t;
    int o = co * CINC + ci;
    float wrow[32];
    #pragma unroll
    for (int c = 0; c < 32; ++c) wrow[c] = w3[o * 32 + c];
    float bb = b3[o];
    int chunk = ci >> 5;
    int g     = (ci >> 3) & 3;
    int j     = ci & 7;
    int lane  = (g << 4) | (co & 15);
    #pragma unroll
    for (int tap = 0; tap < 9; ++tap) {
        float acc = bb;
        #pragma unroll
        for (int c = 0; c < 32; ++c) acc += wrow[c] * k2s[c * 9 + tap];
        size_t frag = ((size_t)(b * 9 + tap) * 2 + chunk) * 4 + (co >> 4);
        wf[frag * 512 + lane * 8 + j] = (_Float16)acc;
    }
}

// ---- Kernel 2: split+transpose x -> xt[b][y][x]{256B: [chunk][plane][g][8 f16]} ----
// Block: 64 pixels (half row) x all 64 ci. 256 threads.
__global__ __launch_bounds__(256)
void xsplit_kernel(const float* __restrict__ x, _Float16* __restrict__ xt) {
    __shared__ __align__(16) char lt[64 * 256];   // 16 KB
    const int xh = blockIdx.x;        // 0..1
    const int y  = blockIdx.y;        // 0..127
    const int b  = blockIdx.z;        // 0..15
    const int t  = threadIdx.x;
    const int cig = t >> 4;           // 0..15 -> 4 consecutive ci
    const int pxq = t & 15;           // 0..15 -> 4 consecutive pixels
    const int chunk = cig >> 3;
    const int g     = (cig >> 1) & 3;
    const int jh    = cig & 1;
    const int ci0   = chunk * 32 + g * 8 + jh * 4;
    const int x0    = xh * 64;

    f32x4 xv[4];
    #pragma unroll
    for (int r = 0; r < 4; ++r)
        xv[r] = *(const f32x4*)(x + (((size_t)(b * CINC + ci0 + r) * HH + y) * WW + x0 + pxq * 4));

    const int off_hi = (chunk << 7) + (g << 4) + (jh << 3);
    #pragma unroll
    for (int ii = 0; ii < 4; ++ii) {
        int px = pxq * 4 + ii;
        f16x4 hv, lv;
        #pragma unroll
        for (int r = 0; r < 4; ++r) {
            float v = xv[r][ii];
            _Float16 hh = (_Float16)v;
            hv[r] = hh;
            lv[r] = (_Float16)(v - (float)hh);
        }
        int sw = (px & 7) << 4;
        *(f16x4*)(lt + (px << 8) + ((off_hi)      ^ sw)) = hv;
        *(f16x4*)(lt + (px << 8) + ((off_hi + 64) ^ sw)) = lv;
    }
    __syncthreads();

    char* dst = (char*)xt + (((size_t)(b * HH + y) * WW + x0) << 8);
    #pragma unroll
    for (int r = 0; r < 4; ++r) {
        int lu = r * 256 + t;
        int px = lu >> 4;
        int sl = lu & 15;
        f16x8 v = *(const f16x8*)(lt + (px << 8) + ((sl ^ (px & 7)) << 4));
        *(f16x8*)(dst + (size_t)lu * 16) = v;
    }
}

// ---- Kernel 3: MFMA conv, 4 waves, single 20.7KB LDS buffer per (chunk,plane) ----
__global__ __launch_bounds__(256)
void conv_mfma2_kernel(const _Float16* __restrict__ xt,
                       const _Float16* __restrict__ wf,
                       const float* __restrict__ bias,
                       const float* __restrict__ zp,
                       float* __restrict__ out) {
    __shared__ __align__(16) char xs[324 * 64];   // 20736 B

    const int b   = blockIdx.z;
    const int x0  = blockIdx.x * 16;
    const int y0  = blockIdx.y * 16;
    const int tid = threadIdx.x;
    const int lane = tid & 63;
    const int w    = tid >> 6;       // wave 0..3, owns rows w*4..w*4+3
    const int lc   = lane & 15;
    const int g    = lane >> 4;

    f32x4 acc[4][4];
    #pragma unroll
    for (int m = 0; m < 4; ++m)
        #pragma unroll
        for (int n = 0; n < 4; ++n)
            acc[m][n] = (f32x4){0.f, 0.f, 0.f, 0.f};

    const char* xtb = (const char*)xt;
    const char* zpb = (const char*)zp;
    const f16x8* wfb = (const f16x8*)wf;

    for (int vc = 0; vc < 4; ++vc) {
        const int chunk = vc >> 1;
        const int plane = vc & 1;
        if (vc) __syncthreads();
        // ---- stage: 1296 16B units; rotation folded into source slot ----
        #pragma unroll
        for (int i = 0; i < 5; ++i) {
            int u = ((i * 4 + w) << 6) + lane;     // 0..1279
            int p = u >> 2, s = u & 3;
            int srow = p / 18;
            int scol = p - srow * 18;
            int gy = y0 - 1 + srow;
            int gx = x0 - 1 + scol;
            const char* gp;
            if ((unsigned)gy < HH && (unsigned)gx < WW)
                gp = xtb + ((((size_t)b * HH + gy) * WW + gx) << 8)
                         + (chunk << 7) + (plane << 6) + (((s - p) & 3) << 4);
            else
                gp = zpb + ((u & 63) << 4);
            f16x8 v = *(const f16x8*)gp;
            *(f16x8*)(xs + (u << 4)) = v;
        }
        if (tid < 16) {                            // tail units 1280..1295
            int u = 1280 + tid;
            int p = u >> 2, s = u & 3;
            int srow = p / 18;
            int scol = p - srow * 18;
            int gy = y0 - 1 + srow;
            int gx = x0 - 1 + scol;
            const char* gp;
            if ((unsigned)gy < HH && (unsigned)gx < WW)
                gp = xtb + ((((size_t)b * HH + gy) * WW + gx) << 8)
                         + (chunk << 7) + (plane << 6) + (((s - p) & 3) << 4);
            else
                gp = zpb + ((u & 63) << 4);
            f16x8 v = *(const f16x8*)gp;
            *(f16x8*)(xs + (u << 4)) = v;
        }
        __syncthreads();

        // ---- compute ----
        #pragma unroll 1
        for (int tap = 0; tap < 9; ++tap) {
            size_t fb = ((size_t)(b * 9 + tap) * 2 + chunk) * 4;
            f16x8 B[4];
            #pragma unroll
            for (int n = 0; n < 4; ++n) B[n] = wfb[(fb + n) * 64 + lane];
            int ky = tap / 3;
            int kx = tap - ky * 3;
            #pragma unroll
            for (int m = 0; m < 4; ++m) {
                int srow = (w << 2) + m + ky;
                int p = srow * 18 + lc + kx;
                f16x8 A = *(const f16x8*)(xs + (p << 6) + (((g + p) & 3) << 4));
                #pragma unroll
                for (int n = 0; n < 4; ++n)
                    acc[m][n] = __builtin_amdgcn_mfma_f32_16x16x32_f16(A, B[n], acc[m][n], 0, 0, 0);
            }
        }
    }

    // ---- epilogue ----
    float bval[4];
    #pragma unroll
    for (int n = 0; n < 4; ++n) bval[n] = bias[n * 16 + lc];
    #pragma unroll
    for (int m = 0; m < 4; ++m) {
        int y  = y0 + (w << 2) + m;
        int xx = x0 + g * 4;
        #pragma unroll
        for (int n = 0; n < 4; ++n) {
            int co = n * 16 + lc;
            f32x4 r = acc[m][n];
            r += bval[n];
            *(f32x4*)(out + (((size_t)(b * COUTC + co) * HH + y) * WW + xx)) = r;
        }
    }
}

extern "C" void kernel_launch(void* const* d_in, const int* in_sizes, int n_in,
                              void* d_out, int out_size, void* d_ws, size_t ws_size,
                              hipStream_t stream) {
    const float* x    = (const float*)d_in[0];
    const float* h    = (const float*)d_in[1];
    const float* fc_w = (const float*)d_in[2];
    const float* fc_b = (const float*)d_in[3];
    const float* w1   = (const float*)d_in[4];
    const float* b1   = (const float*)d_in[5];
    const float* w2   = (const float*)d_in[6];
    const float* b2   = (const float*)d_in[7];
    const float* w3   = (const float*)d_in[8];
    const float* b3   = (const float*)d_in[9];
    const float* bias = (const float*)d_in[10];
    float* out = (float*)d_out;

    // Main-path ws layout: zp (1KB) | wf (1,179,648 B) | xt (67,108,864 B)
    const size_t ZP_BYTES = 1024;
    const size_t WF_BYTES = (size_t)BB * 9 * 2 * 4 * 512 * sizeof(_Float16);  // 1,179,648
    const size_t XT_BYTES = (size_t)BB * HH * WW * 256;                        // 67,108,864
    const size_t NEED = ZP_BYTES + WF_BYTES + XT_BYTES;

    if (ws_size >= NEED) {
        float*     zp = (float*)d_ws;
        _Float16*  wf = (_Float16*)((char*)d_ws + ZP_BYTES);
        _Float16*  xt = (_Float16*)((char*)d_ws + ZP_BYTES + WF_BYTES);
        hyper_fused_kernel<<<dim3(COUTC, BB), dim3(64), 0, stream>>>(
            h, fc_w, fc_b, w1, b1, w2, b2, w3, b3, wf, zp);
        xsplit_kernel<<<dim3(2, HH, BB), dim3(256), 0, stream>>>(x, xt);
        conv_mfma2_kernel<<<dim3(WW / 16, HH / 16, BB), dim3(256), 0, stream>>>(
            xt, wf, bias, zp, out);
    } else {
        // Fallback: round-2 path (needs ~1.2 MB)
        float* k2 = (float*)d_ws;
        _Float16* wfrag = (_Float16*)((char*)d_ws + 18432);
        hyper_k2_kernel<<<dim3(BB), dim3(256), 0, stream>>>(h, fc_w, fc_b, w1, b1, w2, b2, k2);
        hyper_wfrag_kernel<<<dim3(COUTC, BB), dim3(64), 0, stream>>>(k2, w3, b3, wfrag);
        conv_mfma_kernel<<<dim3(WW / 16, HH / 16, BB), dim3(128), 0, stream>>>(x, wfrag, bias, out);
    }
}